// Round 7
// baseline (438.644 us; speedup 1.0000x reference)
//
#include <hip/hip_runtime.h>
#include <stdint.h>

#define N_IMG 8
#define K_INS 16
#define CCH   64
#define SPL   8      // HW split per (n,c): stats 4096 blocks, 5 blocks/CU (LDS-capped)
#define EPSV  1e-5f

typedef float vfloat4 __attribute__((ext_vector_type(4)));

// workspace layout (bytes):
//   [0, 524288)        float2 P[N][K][C][SPL]  partial (sum,sumsq) -- fully written each call
//   [524288, 524800)   int    cnt[N][K]        -- zeroed via hipMemsetAsync each call
#define P_OFF   0
#define CNT_OFF (N_IMG * K_INS * CCH * SPL * 8)

// Non-returning LDS float atomic: fire-and-forget ds_add_f32. No register
// dependency chain (unlike atomicAdd's CAS loop / rtn form); outstanding ops
// are drained by the lgkmcnt(0) the compiler emits before s_barrier.
// LDS byte offset = low 32 bits of the generic pointer (shared aperture is
// 4GB-aligned).
__device__ __forceinline__ void lds_fadd(const float* p, float v) {
    asm volatile("ds_add_f32 %0, %1" ::"v"((uint32_t)(uintptr_t)p), "v"(v));
}

__global__ __launch_bounds__(256) void count_kernel(const int* __restrict__ ids,
                                                    int* __restrict__ cnt, int HW) {
    // grid: (32, N). Register-accumulated ballot histogram; 16 atomics/wave.
    const int n = blockIdx.y;
    const int tileSize = HW / 32;
    const int quarter = tileSize / 4;
    const int lane = threadIdx.x & 63;
    const int wave = threadIdx.x >> 6;
    const int wbase = blockIdx.x * tileSize + wave * quarter;
    const int* p = ids + (size_t)n * HW;

    int myc[K_INS];
#pragma unroll
    for (int k = 0; k < K_INS; ++k) myc[k] = 0;

    for (int i = wbase + lane; i < wbase + quarter; i += 64) {
        int id = p[i];
#pragma unroll
        for (int k = 0; k < K_INS; ++k) {
            unsigned long long m = __ballot(id == k);
            if (lane == 0) myc[k] += __popcll(m);
        }
    }
    if (lane == 0) {
#pragma unroll
        for (int k = 0; k < K_INS; ++k) atomicAdd(&cnt[n * K_INS + k], myc[k]);
    }
}

__global__ __launch_bounds__(256) void stats_kernel(const float* __restrict__ x,
                                                    const int* __restrict__ ids,
                                                    float2* __restrict__ P, int HW) {
    // grid: (C, N, SPL). Block owns chunk sb of (n,c).
    // Scatter-accumulate into per-thread-private LDS cells via non-returning
    // ds_add_f32: acc[k][2t] = sum, acc[k][2t+1] = sumsq. Single writer per
    // cell -> bitwise deterministic. Bank aliasing is 2-way (free).
    const int c = blockIdx.x;
    const int n = blockIdx.y;
    const int sb = blockIdx.z;
    const int t = threadIdx.x;
    const int chunk = HW / SPL;  // 8192

    __shared__ float acc[K_INS * 512];
    for (int i = t; i < K_INS * 512; i += 256) acc[i] = 0.f;
    __syncthreads();

    const float4* x4 = (const float4*)(x + ((size_t)n * CCH + c) * HW + (size_t)sb * chunk);
    const int4* i4 = (const int4*)(ids + (size_t)n * HW + (size_t)sb * chunk);

    float* cell = acc + 2 * t;  // this thread's column; k stride = 512 floats

    const int iters = chunk / (256 * 4);  // 8
#pragma unroll 4
    for (int j = 0; j < iters; ++j) {
        int idx = j * 256 + t;
        float4 xv = x4[idx];
        int4 iv = i4[idx];
        if (iv.x >= 0) {
            lds_fadd(cell + iv.x * 512, xv.x);
            lds_fadd(cell + iv.x * 512 + 1, xv.x * xv.x);
        }
        if (iv.y >= 0) {
            lds_fadd(cell + iv.y * 512, xv.y);
            lds_fadd(cell + iv.y * 512 + 1, xv.y * xv.y);
        }
        if (iv.z >= 0) {
            lds_fadd(cell + iv.z * 512, xv.z);
            lds_fadd(cell + iv.z * 512 + 1, xv.z * xv.z);
        }
        if (iv.w >= 0) {
            lds_fadd(cell + iv.w * 512, xv.w);
            lds_fadd(cell + iv.w * 512 + 1, xv.w * xv.w);
        }
    }
    __syncthreads();

    // reduce 256 float2 cells per k: thread (k = t>>4, seg = t&15) sums 16
    // cells (rotated index to spread banks), then shfl-reduce over 16 lanes.
    const int k = t >> 4;
    const int seg = t & 15;
    const float2* acc2 = (const float2*)acc;
    float rs = 0.f, rq = 0.f;
#pragma unroll
    for (int i = 0; i < 16; ++i) {
        float2 v = acc2[k * 256 + seg * 16 + ((i + seg) & 15)];
        rs += v.x;
        rq += v.y;
    }
#pragma unroll
    for (int off = 8; off > 0; off >>= 1) {
        rs += __shfl_down(rs, off, 16);
        rq += __shfl_down(rq, off, 16);
    }
    if (seg == 0) P[((size_t)(n * K_INS + k) * CCH + c) * SPL + sb] = make_float2(rs, rq);
}

__global__ __launch_bounds__(256) void norm_kernel(const float* __restrict__ x,
                                                   const int* __restrict__ ids,
                                                   const float2* __restrict__ P,
                                                   const int* __restrict__ cnt,
                                                   const float* __restrict__ gamma,
                                                   const float* __restrict__ beta,
                                                   float* __restrict__ out, int HW) {
    // grid: (C, N, SPL). Head: 16 threads fold SPL partials + count -> scale/shift.
    const int c = blockIdx.x;
    const int n = blockIdx.y;
    const int sb = blockIdx.z;
    const int t = threadIdx.x;
    const int chunk = HW / SPL;

    __shared__ float2 ls[K_INS];
    if (t < K_INS) {
        float rs = 0.f, rq = 0.f;
#pragma unroll
        for (int sp = 0; sp < SPL; ++sp) {
            float2 v = P[((size_t)(n * K_INS + t) * CCH + c) * SPL + sp];
            rs += v.x;
            rq += v.y;
        }
        float denom = fmaxf((float)cnt[n * K_INS + t], 1.0f);
        float mean = rs / denom;
        float var = rq / denom - mean * mean;
        float r = rsqrtf(var + EPSV);
        float sc = r * gamma[c];
        float sh = beta[c] - mean * sc;
        ls[t] = make_float2(sc, sh);
    }
    __syncthreads();

    const float4* xp = (const float4*)(x + ((size_t)n * CCH + c) * HW + (size_t)sb * chunk);
    const int4* ip = (const int4*)(ids + (size_t)n * HW + (size_t)sb * chunk);
    vfloat4* op = (vfloat4*)(out + ((size_t)n * CCH + c) * HW + (size_t)sb * chunk);

    const int iters = chunk / (256 * 4);  // 8
#pragma unroll 4
    for (int j = 0; j < iters; ++j) {
        int idx = j * 256 + t;
        float4 xv = xp[idx];
        int4 id = ip[idx];
        vfloat4 o;
        {
            float2 ss = ls[max(id.x, 0)];
            o.x = (id.x >= 0) ? fmaf(xv.x, ss.x, ss.y) : xv.x;
        }
        {
            float2 ss = ls[max(id.y, 0)];
            o.y = (id.y >= 0) ? fmaf(xv.y, ss.x, ss.y) : xv.y;
        }
        {
            float2 ss = ls[max(id.z, 0)];
            o.z = (id.z >= 0) ? fmaf(xv.z, ss.x, ss.y) : xv.z;
        }
        {
            float2 ss = ls[max(id.w, 0)];
            o.w = (id.w >= 0) ? fmaf(xv.w, ss.x, ss.y) : xv.w;
        }
        // out is never re-read: nontemporal store keeps x resident in L3
        __builtin_nontemporal_store(o, &op[idx]);
    }
}

extern "C" void kernel_launch(void* const* d_in, const int* in_sizes, int n_in,
                              void* d_out, int out_size, void* d_ws, size_t ws_size,
                              hipStream_t stream) {
    const float* x = (const float*)d_in[0];
    const int* ids = (const int*)d_in[1];
    const float* gamma = (const float*)d_in[2];
    const float* beta = (const float*)d_in[3];
    float* out = (float*)d_out;

    const int HW = in_sizes[1] / N_IMG;  // 65536

    float2* P = (float2*)((char*)d_ws + P_OFF);
    int* cnt = (int*)((char*)d_ws + CNT_OFF);

    // counts are accumulated with atomics -> must be zeroed every call
    hipMemsetAsync((char*)d_ws + CNT_OFF, 0, N_IMG * K_INS * sizeof(int), stream);

    count_kernel<<<dim3(32, N_IMG), 256, 0, stream>>>(ids, cnt, HW);
    stats_kernel<<<dim3(CCH, N_IMG, SPL), 256, 0, stream>>>(x, ids, P, HW);
    norm_kernel<<<dim3(CCH, N_IMG, SPL), 256, 0, stream>>>(x, ids, P, cnt, gamma, beta, out, HW);
}

// Round 8
// 133.533 us; speedup vs baseline: 3.2849x; 3.2849x over previous
//
#include <hip/hip_runtime.h>
#include <hip/hip_bf16.h>
#include <stdint.h>

#define N_IMG 8
#define K_INS 16
#define CCH   64
#define SB    256    // pixel splits for stats: chunk = HW/SB = 256 px
#define SPLN  8      // HW split for norm
#define EPSV  1e-5f

typedef float vfloat4 __attribute__((ext_vector_type(4)));
typedef short bf16x8 __attribute__((ext_vector_type(8)));
typedef float f32x4 __attribute__((ext_vector_type(4)));

// workspace layout (bytes):
//   [0, 16777216)            float2 P[N][4][SB][256]   partial (sum,sumsq), inner = c_local*16+k
//   [16777216, 16842752)     float2 scsh[N][4][256]    (scale, shift), inner = c_local*16+k
//   [16842752, 16843264)     int    cnt[N][K]          -- zeroed via hipMemsetAsync each call
#define P_OFF    0
#define SCSH_OFF 16777216
#define CNT_OFF  16842752

__device__ __forceinline__ short bf16_bits(float v) {
    __hip_bfloat16 h = __float2bfloat16(v);
    union { __hip_bfloat16 h; short s; } u;
    u.h = h;
    return u.s;
}

__global__ __launch_bounds__(256) void count_kernel(const int* __restrict__ ids,
                                                    int* __restrict__ cnt, int HW) {
    // grid: (32, N). Register-accumulated ballot histogram; 16 atomics/wave.
    const int n = blockIdx.y;
    const int tileSize = HW / 32;
    const int quarter = tileSize / 4;
    const int lane = threadIdx.x & 63;
    const int wave = threadIdx.x >> 6;
    const int wbase = blockIdx.x * tileSize + wave * quarter;
    const int* p = ids + (size_t)n * HW;

    int myc[K_INS];
#pragma unroll
    for (int k = 0; k < K_INS; ++k) myc[k] = 0;

    for (int i = wbase + lane; i < wbase + quarter; i += 64) {
        int id = p[i];
#pragma unroll
        for (int k = 0; k < K_INS; ++k) {
            unsigned long long m = __ballot(id == k);
            if (lane == 0) myc[k] += __popcll(m);
        }
    }
    if (lane == 0) {
#pragma unroll
        for (int k = 0; k < K_INS; ++k) atomicAdd(&cnt[n * K_INS + k], myc[k]);
    }
}

__global__ __launch_bounds__(256) void stats_kernel(const float* __restrict__ x,
                                                    const int* __restrict__ ids,
                                                    float2* __restrict__ P, int HW) {
    // grid: (N, SB). Block: 4 waves = 4 c-blocks over the SAME 256-pixel chunk
    // (ids reads L1-shared across waves). Per wave, per 32-pixel step:
    //   S[c][k] += x[c][p] * mask[p][k] via mfma_f32_16x16x32_bf16
    // A-frag: lane holds x[row=lane&15][p + (lane>>4)*8 + j] (8 contiguous).
    // B-frag: lane holds mask[p...][col=lane&15] = (ids[p+...]==lane&15).
    // A and B share the per-lane k(p)-slice mapping -> pairing is correct.
    // D: col=lane&15 (k), row=(lane>>4)*4+reg (c_local)  [verified layout].
    const int n = blockIdx.x;
    const int sb = blockIdx.y;
    const int t = threadIdx.x;
    const int wave = t >> 6;   // c-block 0..3
    const int lane = t & 63;
    const int row = lane & 15; // channel-within-block for A; instance k for B
    const int kg = lane >> 4;  // p-slice group

    const int chunk = HW / SB;  // 256
    const float* xrow = x + (size_t)(n * CCH + wave * 16 + row) * HW + sb * chunk;
    const int* idp = ids + (size_t)n * HW + sb * chunk;

    f32x4 accS = {0.f, 0.f, 0.f, 0.f};
    f32x4 accQ = {0.f, 0.f, 0.f, 0.f};

#pragma unroll
    for (int s = 0; s < chunk / 32; ++s) {  // 8 steps
        const int p = s * 32 + kg * 8;
        float4 xa = *(const float4*)(xrow + p);
        float4 xb = *(const float4*)(xrow + p + 4);
        int4 ia = *(const int4*)(idp + p);
        int4 ib = *(const int4*)(idp + p + 4);
        float xs[8] = {xa.x, xa.y, xa.z, xa.w, xb.x, xb.y, xb.z, xb.w};
        int iv[8] = {ia.x, ia.y, ia.z, ia.w, ib.x, ib.y, ib.z, ib.w};
        bf16x8 ax, aq, mk;
#pragma unroll
        for (int j = 0; j < 8; ++j) {
            ax[j] = bf16_bits(xs[j]);
            aq[j] = bf16_bits(xs[j] * xs[j]);
            mk[j] = (iv[j] == row) ? (short)0x3F80 : (short)0;  // bf16 1.0 / 0.0
        }
        accS = __builtin_amdgcn_mfma_f32_16x16x32_bf16(ax, mk, accS, 0, 0, 0);
        accQ = __builtin_amdgcn_mfma_f32_16x16x32_bf16(aq, mk, accQ, 0, 0, 0);
    }

    // write per-wave partials: P[n][wave][sb][c_local*16 + k], k = row
    float2* Pb = P + (size_t)((n * 4 + wave) * SB + sb) * 256;
#pragma unroll
    for (int r = 0; r < 4; ++r) {
        Pb[(kg * 4 + r) * 16 + row] = make_float2(accS[r], accQ[r]);
    }
}

__global__ __launch_bounds__(256) void finalize_kernel(const float2* __restrict__ P,
                                                       const int* __restrict__ cnt,
                                                       const float* __restrict__ gamma,
                                                       const float* __restrict__ beta,
                                                       float2* __restrict__ scsh) {
    // grid: (4, N). thread t <-> (c_local = t>>4, k = t&15). 256 coalesced
    // 2KB passes over P, then scale/shift.
    const int cb = blockIdx.x;
    const int n = blockIdx.y;
    const int t = threadIdx.x;
    const float2* Pb = P + (size_t)(n * 4 + cb) * SB * 256;

    float rs = 0.f, rq = 0.f;
#pragma unroll 8
    for (int sb = 0; sb < SB; ++sb) {
        float2 v = Pb[(size_t)sb * 256 + t];
        rs += v.x;
        rq += v.y;
    }
    const int c = cb * 16 + (t >> 4);
    const int k = t & 15;
    float denom = fmaxf((float)cnt[n * K_INS + k], 1.0f);
    float mean = rs / denom;
    float var = rq / denom - mean * mean;
    float r = rsqrtf(var + EPSV);
    float sc = r * gamma[c];
    float sh = beta[c] - mean * sc;
    scsh[(n * 4 + cb) * 256 + t] = make_float2(sc, sh);
}

__global__ __launch_bounds__(256) void norm_kernel(const float* __restrict__ x,
                                                   const int* __restrict__ ids,
                                                   const float2* __restrict__ scsh,
                                                   float* __restrict__ out, int HW) {
    // grid: (C, N, SPLN). Head: 16 threads load this (n,c)'s 16 scale/shift.
    const int c = blockIdx.x;
    const int n = blockIdx.y;
    const int sb = blockIdx.z;
    const int t = threadIdx.x;
    const int chunk = HW / SPLN;

    __shared__ float2 ls[K_INS];
    if (t < K_INS) ls[t] = scsh[(n * 4 + (c >> 4)) * 256 + (c & 15) * 16 + t];
    __syncthreads();

    const float4* xp = (const float4*)(x + ((size_t)n * CCH + c) * HW + (size_t)sb * chunk);
    const int4* ip = (const int4*)(ids + (size_t)n * HW + (size_t)sb * chunk);
    vfloat4* op = (vfloat4*)(out + ((size_t)n * CCH + c) * HW + (size_t)sb * chunk);

    const int iters = chunk / (256 * 4);  // 8
#pragma unroll 4
    for (int j = 0; j < iters; ++j) {
        int idx = j * 256 + t;
        float4 xv = xp[idx];
        int4 id = ip[idx];
        vfloat4 o;
        {
            float2 ss = ls[max(id.x, 0)];
            o.x = (id.x >= 0) ? fmaf(xv.x, ss.x, ss.y) : xv.x;
        }
        {
            float2 ss = ls[max(id.y, 0)];
            o.y = (id.y >= 0) ? fmaf(xv.y, ss.x, ss.y) : xv.y;
        }
        {
            float2 ss = ls[max(id.z, 0)];
            o.z = (id.z >= 0) ? fmaf(xv.z, ss.x, ss.y) : xv.z;
        }
        {
            float2 ss = ls[max(id.w, 0)];
            o.w = (id.w >= 0) ? fmaf(xv.w, ss.x, ss.y) : xv.w;
        }
        // out is never re-read: nontemporal store keeps x resident in L3
        __builtin_nontemporal_store(o, &op[idx]);
    }
}

extern "C" void kernel_launch(void* const* d_in, const int* in_sizes, int n_in,
                              void* d_out, int out_size, void* d_ws, size_t ws_size,
                              hipStream_t stream) {
    const float* x = (const float*)d_in[0];
    const int* ids = (const int*)d_in[1];
    const float* gamma = (const float*)d_in[2];
    const float* beta = (const float*)d_in[3];
    float* out = (float*)d_out;

    const int HW = in_sizes[1] / N_IMG;  // 65536

    float2* P = (float2*)((char*)d_ws + P_OFF);
    float2* scsh = (float2*)((char*)d_ws + SCSH_OFF);
    int* cnt = (int*)((char*)d_ws + CNT_OFF);

    // counts are accumulated with atomics -> must be zeroed every call
    hipMemsetAsync((char*)d_ws + CNT_OFF, 0, N_IMG * K_INS * sizeof(int), stream);

    count_kernel<<<dim3(32, N_IMG), 256, 0, stream>>>(ids, cnt, HW);
    stats_kernel<<<dim3(N_IMG, SB), 256, 0, stream>>>(x, ids, P, HW);
    finalize_kernel<<<dim3(4, N_IMG), 256, 0, stream>>>(P, cnt, gamma, beta, scsh);
    norm_kernel<<<dim3(CCH, N_IMG, SPLN), 256, 0, stream>>>(x, ids, scsh, out, HW);
}

// Round 9
// 88.708 us; speedup vs baseline: 4.9448x; 1.5053x over previous
//
#include <hip/hip_runtime.h>
#include <hip/hip_bf16.h>
#include <stdint.h>

#define N_IMG 8
#define K_INS 16
#define CCH   64
#define SB    256    // pixel chunks: chunk = HW/SB = 256 px
#define PXC   256    // norm pixel chunk
#define EPSV  1e-5f

typedef float vfloat4 __attribute__((ext_vector_type(4)));
typedef short bf16x8 __attribute__((ext_vector_type(8)));
typedef float f32x4 __attribute__((ext_vector_type(4)));

// workspace layout (bytes):
//   [0, 16777216)            float2 P[N][4][SB][256]  partial (sum,sumsq), inner = c_local*16+k
//   [16777216, 16908288)     float  P2[N][SB][16]     partial counts per k
//   [16908288, 16973824)     float2 scsh[N][C][K]     (scale, shift)
// all fully written each call; no atomics anywhere -> deterministic, no memset.
#define P_OFF    0
#define P2_OFF   16777216
#define SCSH_OFF 16908288

__device__ __forceinline__ short bf16_bits(float v) {
    __hip_bfloat16 h = __float2bfloat16(v);
    union { __hip_bfloat16 h; short s; } u;
    u.h = h;
    return u.s;
}

__global__ __launch_bounds__(256) void stats_kernel(const float* __restrict__ x,
                                                    const int* __restrict__ ids,
                                                    float2* __restrict__ P,
                                                    float* __restrict__ P2, int HW) {
    // grid: (N, SB). Block: 4 waves = 4 c-blocks over the SAME 256-pixel chunk.
    //   S[c][k] += x[c][p] * mask[p][k]   via mfma_f32_16x16x32_bf16
    //   Q[c][k] += x^2 ... ; Cnt[k] += 1 * mask (A = ones, exact in f32)
    // A-frag: lane holds x[row=lane&15][p + (lane>>4)*8 + j] (8 contiguous).
    // B-frag: lane holds mask[p...][col=lane&15] = (ids[p+...]==lane&15).
    // D: col=lane&15 (k), row=(lane>>4)*4+reg (c_local)  [verified layout].
    const int n = blockIdx.x;
    const int sb = blockIdx.y;
    const int t = threadIdx.x;
    const int wave = t >> 6;   // c-block 0..3
    const int lane = t & 63;
    const int row = lane & 15; // channel-within-block for A; instance k for B
    const int kg = lane >> 4;  // p-slice group

    const int chunk = HW / SB;  // 256
    const float* xrow = x + (size_t)(n * CCH + wave * 16 + row) * HW + sb * chunk;
    const int* idp = ids + (size_t)n * HW + sb * chunk;

    f32x4 accS = {0.f, 0.f, 0.f, 0.f};
    f32x4 accQ = {0.f, 0.f, 0.f, 0.f};
    f32x4 accC = {0.f, 0.f, 0.f, 0.f};
    bf16x8 ones;
#pragma unroll
    for (int j = 0; j < 8; ++j) ones[j] = (short)0x3F80;  // bf16 1.0

#pragma unroll
    for (int s = 0; s < chunk / 32; ++s) {  // 8 steps
        const int p = s * 32 + kg * 8;
        float4 xa = *(const float4*)(xrow + p);
        float4 xb = *(const float4*)(xrow + p + 4);
        int4 ia = *(const int4*)(idp + p);
        int4 ib = *(const int4*)(idp + p + 4);
        float xs[8] = {xa.x, xa.y, xa.z, xa.w, xb.x, xb.y, xb.z, xb.w};
        int iv[8] = {ia.x, ia.y, ia.z, ia.w, ib.x, ib.y, ib.z, ib.w};
        bf16x8 ax, aq, mk;
#pragma unroll
        for (int j = 0; j < 8; ++j) {
            ax[j] = bf16_bits(xs[j]);
            aq[j] = bf16_bits(xs[j] * xs[j]);
            mk[j] = (iv[j] == row) ? (short)0x3F80 : (short)0;
        }
        accS = __builtin_amdgcn_mfma_f32_16x16x32_bf16(ax, mk, accS, 0, 0, 0);
        accQ = __builtin_amdgcn_mfma_f32_16x16x32_bf16(aq, mk, accQ, 0, 0, 0);
        accC = __builtin_amdgcn_mfma_f32_16x16x32_bf16(ones, mk, accC, 0, 0, 0);
    }

    // write per-wave partials: P[n][wave][sb][c_local*16 + k], k = row
    float2* Pb = P + (size_t)((n * 4 + wave) * SB + sb) * 256;
#pragma unroll
    for (int r = 0; r < 4; ++r) {
        Pb[(kg * 4 + r) * 16 + row] = make_float2(accS[r], accQ[r]);
    }
    // counts: wave 0, kg==0 (t<16), reg 0 -> c_local 0, k = t (rows identical)
    if (t < 16) P2[((size_t)n * SB + sb) * 16 + t] = accC[0];
}

__global__ __launch_bounds__(256) void finalize_kernel(const float2* __restrict__ P,
                                                       const float* __restrict__ P2,
                                                       const float* __restrict__ gamma,
                                                       const float* __restrict__ beta,
                                                       float2* __restrict__ scsh) {
    // grid: (4, N). thread t <-> (c_local = t>>4, k = t&15).
    const int cb = blockIdx.x;
    const int n = blockIdx.y;
    const int t = threadIdx.x;

    // counts: thread t sums its 16 sb-slices for k=t&15, LDS-reduce across groups
    __shared__ float csh[16][17];
    const float* P2n = P2 + (size_t)n * SB * 16;
    float cc = 0.f;
#pragma unroll 4
    for (int i = 0; i < 16; ++i) cc += P2n[((t >> 4) * 16 + i) * 16 + (t & 15)];
    csh[t >> 4][t & 15] = cc;

    const float2* Pb = P + (size_t)(n * 4 + cb) * SB * 256;
    float rs = 0.f, rq = 0.f;
#pragma unroll 16
    for (int sb = 0; sb < SB; ++sb) {
        float2 v = Pb[(size_t)sb * 256 + t];
        rs += v.x;
        rq += v.y;
    }
    __syncthreads();
    float cnt = 0.f;
#pragma unroll
    for (int i = 0; i < 16; ++i) cnt += csh[i][t & 15];

    const int c = cb * 16 + (t >> 4);
    const int k = t & 15;
    float denom = fmaxf(cnt, 1.0f);
    float mean = rs / denom;
    float var = rq / denom - mean * mean;
    float r = rsqrtf(var + EPSV);
    float sc = r * gamma[c];
    float sh = beta[c] - mean * sc;
    scsh[((size_t)n * CCH + c) * K_INS + k] = make_float2(sc, sh);
}

__global__ __launch_bounds__(256) void norm_kernel(const float* __restrict__ x,
                                                   const int* __restrict__ ids,
                                                   const float2* __restrict__ scsh,
                                                   float* __restrict__ out, int HW) {
    // grid: (HW/PXC, N). Block owns 256 pixels x ALL 64 channels:
    // ids loaded ONCE per lane (4 px) and reused across channels; full
    // (c,k) scale/shift table (8 KB) staged in LDS. Per c-iteration the
    // table gather has <=16 distinct addresses on 16 distinct bank-pairs
    // -> broadcast, conflict-free. x loads dense 1KB/wave-instr.
    const int sb = blockIdx.x;
    const int n = blockIdx.y;
    const int t = threadIdx.x;
    const int lane = t & 63;
    const int wave = t >> 6;
    const int px0 = sb * PXC;

    int4 myid = *(const int4*)(ids + (size_t)n * HW + px0 + lane * 4);

    __shared__ float2 ls[CCH * K_INS];
    const float4* src = (const float4*)(scsh + (size_t)n * CCH * K_INS);
    ((float4*)ls)[t] = src[t];
    ((float4*)ls)[t + 256] = src[t + 256];
    __syncthreads();

    const int i0 = max(myid.x, 0), i1 = max(myid.y, 0);
    const int i2 = max(myid.z, 0), i3 = max(myid.w, 0);

#pragma unroll 4
    for (int ci = 0; ci < 16; ++ci) {
        const int c = wave * 16 + ci;
        const float* xr = x + ((size_t)n * CCH + c) * HW + px0;
        float4 xv = *(const float4*)(xr + lane * 4);
        const float2* lc = ls + c * K_INS;
        float2 s0 = lc[i0], s1 = lc[i1], s2 = lc[i2], s3 = lc[i3];
        vfloat4 o;
        o.x = (myid.x >= 0) ? fmaf(xv.x, s0.x, s0.y) : xv.x;
        o.y = (myid.y >= 0) ? fmaf(xv.y, s1.x, s1.y) : xv.y;
        o.z = (myid.z >= 0) ? fmaf(xv.z, s2.x, s2.y) : xv.z;
        o.w = (myid.w >= 0) ? fmaf(xv.w, s3.x, s3.y) : xv.w;
        // out is never re-read: nontemporal store keeps x resident in L3
        __builtin_nontemporal_store(o, (vfloat4*)(out + ((size_t)n * CCH + c) * HW + px0) + lane);
    }
}

extern "C" void kernel_launch(void* const* d_in, const int* in_sizes, int n_in,
                              void* d_out, int out_size, void* d_ws, size_t ws_size,
                              hipStream_t stream) {
    const float* x = (const float*)d_in[0];
    const int* ids = (const int*)d_in[1];
    const float* gamma = (const float*)d_in[2];
    const float* beta = (const float*)d_in[3];
    float* out = (float*)d_out;

    const int HW = in_sizes[1] / N_IMG;  // 65536

    float2* P = (float2*)((char*)d_ws + P_OFF);
    float* P2 = (float*)((char*)d_ws + P2_OFF);
    float2* scsh = (float2*)((char*)d_ws + SCSH_OFF);

    stats_kernel<<<dim3(N_IMG, SB), 256, 0, stream>>>(x, ids, P, P2, HW);
    finalize_kernel<<<dim3(4, N_IMG), 256, 0, stream>>>(P, P2, gamma, beta, scsh);
    norm_kernel<<<dim3(HW / PXC, N_IMG), 256, 0, stream>>>(x, ids, scsh, out, HW);
}